// Round 1
// baseline (451.094 us; speedup 1.0000x reference)
//
#include <hip/hip_runtime.h>
#include <math.h>

// B=4, N=256, D=256, H=8, DK=32, DV=32, R=64
constexpr int B_ = 4, N_ = 256, D_ = 256, H_ = 8, DK_ = 32, DV_ = 32, R_ = 64;
constexpr float SCALE_ = 0.17677669529663687f;  // 1/sqrt(32)
constexpr float EPS_ = 1e-6f;

// ---------------------------------------------------------------------------
// K1: Ek = relationE @ Wr, Ev = relationE @ Wvv   ([64,256] @ [256,256])
__global__ __launch_bounds__(256) void ekev_kernel(
        const float* __restrict__ relE, const float* __restrict__ Wr,
        const float* __restrict__ Wvv, float* __restrict__ Ek,
        float* __restrict__ Ev) {
    int r = blockIdx.x & 63;
    int which = blockIdx.x >> 6;
    const float* W = which ? Wvv : Wr;
    float* out = which ? Ev : Ek;
    __shared__ float row[256];
    int tid = threadIdx.x;
    row[tid] = relE[r * 256 + tid];
    __syncthreads();
    float acc = 0.f;
    for (int d = 0; d < 256; ++d) acc += row[d] * W[d * 256 + tid];
    out[r * 256 + tid] = acc;
}

// ---------------------------------------------------------------------------
// K2: Mcat[d, h*64+r] = sum_dk Wq[d, h*32+dk] * Ek[r, h*32+dk]
__global__ __launch_bounds__(256) void mcat_kernel(
        const float* __restrict__ Wq, const float* __restrict__ Ek,
        float* __restrict__ M) {
    int d = blockIdx.x;
    int t = threadIdx.x;
    __shared__ float wrow[256];
    wrow[t] = Wq[d * 256 + t];
    __syncthreads();
    for (int hr = t; hr < 512; hr += 256) {
        int h = hr >> 6, r = hr & 63;
        const float4* ek4 = (const float4*)(Ek + r * 256 + h * 32);
        const float4* w4 = (const float4*)(wrow + h * 32);
        float acc = 0.f;
#pragma unroll
        for (int k = 0; k < 8; ++k) {
            float4 e = ek4[k], w = w4[k];
            acc += e.x * w.x + e.y * w.y + e.z * w.z + e.w * w.w;
        }
        M[d * 512 + hr] = acc;
    }
}

// ---------------------------------------------------------------------------
// K3: fused projection GEMM: [1024 x 1280] = q[1024,256] @ cat(Wq,Wk,Wv,Mcat)
// 64x64 tile, 16x16 threads, 4x4 acc. grid = 20*16 = 320.
__global__ __launch_bounds__(256) void projT_kernel(
        const float* __restrict__ q, const float* __restrict__ Wq,
        const float* __restrict__ Wk, const float* __restrict__ Wv,
        const float* __restrict__ M, float* __restrict__ Xq,
        float* __restrict__ Xk, float* __restrict__ Xv,
        float* __restrict__ T) {
    int ct = blockIdx.x >> 4, rt = blockIdx.x & 15;
    int t = threadIdx.x;
    __shared__ float ash[32 * 65];
    __shared__ float bsh[32 * 64];
    const float* W;
    int ncols, cbase;
    if (ct < 4)       { W = Wq; cbase = ct * 64;        ncols = 256; }
    else if (ct < 8)  { W = Wk; cbase = (ct - 4) * 64;  ncols = 256; }
    else if (ct < 12) { W = Wv; cbase = (ct - 8) * 64;  ncols = 256; }
    else              { W = M;  cbase = (ct - 12) * 64; ncols = 512; }
    int ti = t >> 4, tj = t & 15;
    float acc[4][4] = {{0.f}};
    for (int kc = 0; kc < 8; ++kc) {
        __syncthreads();
#pragma unroll
        for (int kk = 0; kk < 2; ++kk) {
            int m = t + kk * 256;
            int i = m >> 3, kq = m & 7;
            float4 v = *(const float4*)(q + (size_t)(rt * 64 + i) * 256 + kc * 32 + kq * 4);
            ash[(kq * 4 + 0) * 65 + i] = v.x;
            ash[(kq * 4 + 1) * 65 + i] = v.y;
            ash[(kq * 4 + 2) * 65 + i] = v.z;
            ash[(kq * 4 + 3) * 65 + i] = v.w;
        }
#pragma unroll
        for (int kk = 0; kk < 2; ++kk) {
            int m = t + kk * 256;
            int k = m >> 4, j4 = m & 15;
            float4 v = *(const float4*)(W + (size_t)(kc * 32 + k) * ncols + cbase + j4 * 4);
            *(float4*)(bsh + k * 64 + j4 * 4) = v;
        }
        __syncthreads();
#pragma unroll 8
        for (int k = 0; k < 32; ++k) {
            float4 av = *(const float4*)(ash + k * 65 + ti * 4);
            float4 bv = *(const float4*)(bsh + k * 64 + tj * 4);
            acc[0][0] += av.x * bv.x; acc[0][1] += av.x * bv.y;
            acc[0][2] += av.x * bv.z; acc[0][3] += av.x * bv.w;
            acc[1][0] += av.y * bv.x; acc[1][1] += av.y * bv.y;
            acc[1][2] += av.y * bv.z; acc[1][3] += av.y * bv.w;
            acc[2][0] += av.z * bv.x; acc[2][1] += av.z * bv.y;
            acc[2][2] += av.z * bv.z; acc[2][3] += av.z * bv.w;
            acc[3][0] += av.w * bv.x; acc[3][1] += av.w * bv.y;
            acc[3][2] += av.w * bv.z; acc[3][3] += av.w * bv.w;
        }
    }
    if (ct < 12) {
        float* dst = (ct < 4) ? Xq : (ct < 8) ? Xk : Xv;
        int gcol = (ct & 3) * 64 + tj * 4;
        int h = gcol >> 5, dk = gcol & 31;
#pragma unroll
        for (int a = 0; a < 4; ++a) {
            int row = rt * 64 + ti * 4 + a;
            int bb = row >> 8, n = row & 255;
            *(float4*)(dst + ((size_t)(bb * 8 + h) * 256 + n) * 32 + dk) =
                make_float4(acc[a][0], acc[a][1], acc[a][2], acc[a][3]);
        }
    } else {
        int gcol = (ct - 12) * 64 + tj * 4;
#pragma unroll
        for (int a = 0; a < 4; ++a) {
            int row = rt * 64 + ti * 4 + a;
            *(float4*)(T + (size_t)row * 512 + gcol) =
                make_float4(acc[a][0], acc[a][1], acc[a][2], acc[a][3]);
        }
    }
}

// ---------------------------------------------------------------------------
// async 16B global -> LDS copy (wave-uniform LDS base + lane*16; per-lane src)
__device__ __forceinline__ void async_cp16(void* lds, const void* g) {
    __builtin_amdgcn_global_load_lds(
        (const __attribute__((address_space(1))) void*)g,
        (__attribute__((address_space(3))) void*)lds, 16, 0, 0);
}

// ---------------------------------------------------------------------------
// K5: fused qk + bias + softmax + S per (b,i). grid = 1024, block = 256.
// Wave g owns j-chunk [64g, 64g+64): stages its own 16 KB of link via
// global_load_lds (pre-swizzled SOURCE address, linear LDS dest -> swizzled
// layout, guide m173), computes qk[h][j] from L2-hot Xk, waits only its own
// vmcnt(0) (no barrier), adds the relation bias from LDS, wave-level softmax,
// then S partials from the SAME LDS link copy (no global re-read).
// LDS = 64K link + 8K alpha + 8K union{T,xq,red}/partS = exactly 80 KB
// -> 2 blocks/CU; 5 barriers total (was ~12).
__global__ __launch_bounds__(256) void biassmqk_kernel(
        const float* __restrict__ link, const float* __restrict__ Tg,
        const float* __restrict__ Xq, const float* __restrict__ Xk,
        const int* __restrict__ mask, float* __restrict__ alpha,
        float* __restrict__ S) {
    // bijective XCD swizzle: 1024 blocks = 8 * 128
    int bi = ((blockIdx.x & 7) << 7) | (blockIdx.x >> 3);
    int b = bi >> 8, i = bi & 255;
    int t = threadIdx.x;
    int g = t >> 6, l = t & 63;          // wave, lane
    int j = g * 64 + l;                  // this lane's j (bias/softmax phases)

    __shared__ float linksh[16384];      // 64 KB: [4 chunks][64 j][16 f4 slots]
    __shared__ float absh[2048];         // 8 KB:  alpha [8 h][256 j]
    __shared__ float uni[2048];          // 8 KB:  T[0..511] qx[512..767]
                                         //        red[768..831]; partS later

    // cooperative loads of T row and Xq row (tiny)
    uni[t]       = Tg[(size_t)bi * 512 + t];
    uni[256 + t] = Tg[(size_t)bi * 512 + 256 + t];
    uni[512 + t] = Xq[(((size_t)(b * 8 + (t >> 5))) * 256 + i) * 32 + (t & 31)];
    __syncthreads();                                            // B1

    // ---- per-wave async link staging (AFTER B1 so the barrier's vmcnt(0)
    //      drain doesn't serialize it). LDS linear; source pre-swizzled so
    //      row j holds source float4 rq at slot (rq ^ (j&15)).
    {
        const float* gsrc = link + (((size_t)bi * 256 + g * 64) * 64);
        float* ldst = linksh + g * 4096;
        int jl = l >> 4, sl = l & 15;
#pragma unroll
        for (int k = 0; k < 16; ++k) {
            int jj = k * 4 + jl;
            int rq = sl ^ (jj & 15);
            async_cp16(ldst + k * 256, gsrc + jj * 64 + rq * 4);
        }
    }
    int mv = mask[((size_t)(b * 256 + i)) * 256 + j];

    // ---- qk[h][j] = Xq[b,h,i,:] . Xk[b,h,j,:]  (L2-hot, overlaps staging of
    //      other waves; this wave's consumption drains behind link loads,
    //      which is fine — we need both before the bias anyway)
    float s[8];
#pragma unroll
    for (int h = 0; h < 8; ++h) {
        const float4* xk4 = (const float4*)(Xk + (((size_t)(b * 8 + h)) * 256 + j) * 32);
        const float4* qx4 = (const float4*)(uni + 512 + h * 32);
        float acc = 0.f;
#pragma unroll
        for (int kq = 0; kq < 8; ++kq) {
            float4 xv = xk4[kq], qv = qx4[kq];
            acc += xv.x * qv.x + xv.y * qv.y + xv.z * qv.z + xv.w * qv.w;
        }
        s[h] = acc;
    }

    // ---- wait own link chunk (per-wave, no barrier), then relation bias
    asm volatile("s_waitcnt vmcnt(0)" ::: "memory");
    __builtin_amdgcn_sched_barrier(0);
    {
        const float4* lk4 = ((const float4*)linksh) + g * 1024 + l * 16;
        const float4* T4 = (const float4*)uni;
#pragma unroll
        for (int rq = 0; rq < 16; ++rq) {
            float4 lv = lk4[rq ^ (l & 15)];
#pragma unroll
            for (int h = 0; h < 8; ++h) {
                float4 tv = T4[h * 16 + rq];
                s[h] += lv.x * tv.x + lv.y * tv.y + lv.z * tv.z + lv.w * tv.w;
            }
        }
    }
#pragma unroll
    for (int h = 0; h < 8; ++h) s[h] = (mv == 0) ? -1e9f : s[h] * SCALE_;

    // ---- softmax over j (wave reduce + tiny cross-wave reduce)
    float* redsh = uni + 768;
#pragma unroll
    for (int h = 0; h < 8; ++h) {
        float v = s[h];
        for (int off = 32; off > 0; off >>= 1) v = fmaxf(v, __shfl_xor(v, off));
        if (l == 0) redsh[h * 4 + g] = v;
    }
    __syncthreads();                                            // B2
    float mx[8];
#pragma unroll
    for (int h = 0; h < 8; ++h)
        mx[h] = fmaxf(fmaxf(redsh[h * 4 + 0], redsh[h * 4 + 1]),
                      fmaxf(redsh[h * 4 + 2], redsh[h * 4 + 3]));
#pragma unroll
    for (int h = 0; h < 8; ++h) {
        float e = __expf(s[h] - mx[h]);
        s[h] = e;
        float v = e;
        for (int off = 32; off > 0; off >>= 1) v += __shfl_xor(v, off);
        if (l == 0) redsh[32 + h * 4 + g] = v;
    }
    __syncthreads();                                            // B3
#pragma unroll
    for (int h = 0; h < 8; ++h) {
        float esum = redsh[32 + h * 4 + 0] + redsh[32 + h * 4 + 1] +
                     redsh[32 + h * 4 + 2] + redsh[32 + h * 4 + 3];
        float a = s[h] * (1.f / esum);
        absh[h * 256 + j] = a;
        alpha[((size_t)(b * 8 + h) * 256 + i) * 256 + j] = a;
    }
    __syncthreads();   // B4: all waves done with T/qx/red -> uni reusable

    // ---- S[h][r] partials: wave g sums over its own j-chunk from its own
    //      LDS link copy (lane = r). Swizzled float index in row jj is just
    //      l ^ ((jj&15)<<2)  (XOR involution, 2-way bank aliasing = free).
    {
        const float* lks = linksh + g * 4096;
        float pacc[8] = {0.f, 0.f, 0.f, 0.f, 0.f, 0.f, 0.f, 0.f};
#pragma unroll
        for (int j4 = 0; j4 < 16; ++j4) {
            int j0 = j4 * 4;
            float l0 = lks[(j0 + 0) * 64 + (l ^ (((j0 + 0) & 15) << 2))];
            float l1 = lks[(j0 + 1) * 64 + (l ^ (((j0 + 1) & 15) << 2))];
            float l2 = lks[(j0 + 2) * 64 + (l ^ (((j0 + 2) & 15) << 2))];
            float l3 = lks[(j0 + 3) * 64 + (l ^ (((j0 + 3) & 15) << 2))];
#pragma unroll
            for (int h = 0; h < 8; ++h) {
                float4 av = *(const float4*)(absh + h * 256 + g * 64 + j0);
                pacc[h] += av.x * l0 + av.y * l1 + av.z * l2 + av.w * l3;
            }
        }
        float* partS = uni;  // [4][512] overlays T/qx/red (dead, B4 passed)
#pragma unroll
        for (int h = 0; h < 8; ++h) partS[g * 512 + h * 64 + l] = pacc[h];
    }
    __syncthreads();                                            // B5
    {
        const float* partS = uni;
        for (int hr = t; hr < 512; hr += 256)
            S[(size_t)bi * 512 + hr] = partS[hr] + partS[512 + hr] +
                                       partS[1024 + hr] + partS[1536 + hr];
    }
}

// ---------------------------------------------------------------------------
// K6: fused Z + output: Z[h][dv] = alpha.Xv + S.Ev, then @Wo + residual -> LN.
// grid = 512 (2 rows each), block = 256.
__global__ __launch_bounds__(256) void zout_kernel(
        const float* __restrict__ alpha, const float* __restrict__ Xv,
        const float* __restrict__ S, const float* __restrict__ Ev,
        const float* __restrict__ Wo, const float* __restrict__ q,
        const float* __restrict__ gamma, const float* __restrict__ beta,
        float* __restrict__ out) {
    int blk = blockIdx.x;
    int row0 = blk * 2;                 // rows row0, row0+1 (same b)
    int b = row0 >> 8;
    int t = threadIdx.x;
    __shared__ float Ssh[2 * 512];      // 4 KB
    __shared__ float ashm[2 * 2048];    // alpha [rr][h][j] 16 KB
    __shared__ float zsh[2 * 256];      // 2 KB
    __shared__ float redsh[16];
    for (int m = t; m < 1024; m += 256)
        Ssh[m] = S[(size_t)(row0 + (m >> 9)) * 512 + (m & 511)];
    for (int m = t; m < 4096; m += 256) {
        int rr = m >> 11, h = (m >> 8) & 7, j = m & 255;
        ashm[m] = alpha[((size_t)(b * 8 + h) * 256 + ((row0 + rr) & 255)) * 256 + j];
    }
    __syncthreads();
    // phase 1: Z for both rows
    {
        int h = t >> 5, dv = t & 31;
        float z0 = 0.f, z1 = 0.f;
        const float* xv = Xv + ((size_t)(b * 8 + h) * 256) * 32 + dv;
#pragma unroll 4
        for (int j = 0; j < 256; ++j) {
            float x = xv[j * 32];
            z0 += ashm[h * 256 + j] * x;
            z1 += ashm[2048 + h * 256 + j] * x;
        }
#pragma unroll 4
        for (int r = 0; r < 64; ++r) {
            float ev = Ev[r * 256 + h * 32 + dv];
            z0 += Ssh[h * 64 + r] * ev;
            z1 += Ssh[512 + h * 64 + r] * ev;
        }
        zsh[t] = z0;
        zsh[256 + t] = z1;
    }
    __syncthreads();
    // phase 2: @Wo + residual + LayerNorm (col = t)
    float a0 = q[(size_t)row0 * 256 + t];
    float a1 = q[(size_t)(row0 + 1) * 256 + t];
    for (int d4 = 0; d4 < 64; ++d4) {
        float w0 = Wo[(d4 * 4 + 0) * 256 + t];
        float w1 = Wo[(d4 * 4 + 1) * 256 + t];
        float w2 = Wo[(d4 * 4 + 2) * 256 + t];
        float w3 = Wo[(d4 * 4 + 3) * 256 + t];
        float4 z0v = *(const float4*)(zsh + d4 * 4);
        float4 z1v = *(const float4*)(zsh + 256 + d4 * 4);
        a0 += z0v.x * w0 + z0v.y * w1 + z0v.z * w2 + z0v.w * w3;
        a1 += z1v.x * w0 + z1v.y * w1 + z1v.z * w2 + z1v.w * w3;
    }
    int lane = t & 63, wv = t >> 6;
    float acc2[2] = {a0, a1};
#pragma unroll
    for (int rr = 0; rr < 2; ++rr) {
        float v = acc2[rr], v2 = acc2[rr] * acc2[rr];
        for (int off = 32; off > 0; off >>= 1) {
            v += __shfl_xor(v, off);
            v2 += __shfl_xor(v2, off);
        }
        if (lane == 0) {
            redsh[rr * 8 + wv] = v;
            redsh[rr * 8 + 4 + wv] = v2;
        }
    }
    __syncthreads();
#pragma unroll
    for (int rr = 0; rr < 2; ++rr) {
        float sum = redsh[rr * 8 + 0] + redsh[rr * 8 + 1] + redsh[rr * 8 + 2] + redsh[rr * 8 + 3];
        float sum2 = redsh[rr * 8 + 4] + redsh[rr * 8 + 5] + redsh[rr * 8 + 6] + redsh[rr * 8 + 7];
        float mu = sum * (1.f / 256.f);
        float var = sum2 * (1.f / 256.f) - mu * mu;
        float dev = acc2[rr] - mu;
        out[(size_t)(row0 + rr) * 256 + t] = dev * rsqrtf(var + EPS_) * gamma[t] + beta[t];
    }
}

// ---------------------------------------------------------------------------
extern "C" void kernel_launch(void* const* d_in, const int* in_sizes, int n_in,
                              void* d_out, int out_size, void* d_ws, size_t ws_size,
                              hipStream_t stream) {
    const float* q     = (const float*)d_in[0];
    const int*   mask  = (const int*)d_in[3];
    const float* link  = (const float*)d_in[4];
    const float* Wq    = (const float*)d_in[5];
    const float* Wk    = (const float*)d_in[6];
    const float* Wr    = (const float*)d_in[7];
    const float* Wv    = (const float*)d_in[8];
    const float* Wvv   = (const float*)d_in[9];
    const float* relE  = (const float*)d_in[10];
    const float* Wo    = (const float*)d_in[11];
    const float* gamma = (const float*)d_in[12];
    const float* beta  = (const float*)d_in[13];

    float* out   = (float*)d_out;
    float* alpha = out + B_ * N_ * D_;      // second output [B,H,N,N]

    float* ws    = (float*)d_ws;
    float* Ek    = ws;                         // 16384
    float* Ev    = Ek + 16384;                 // 16384
    float* Mcat  = Ev + 16384;                 // 131072
    float* Xq    = Mcat + 131072;              // 262144
    float* Xk    = Xq + 262144;                // 262144
    float* Xv    = Xk + 262144;                // 262144
    float* T     = Xv + 262144;                // 524288
    float* S     = T + 524288;                 // 524288  (total ~7.9 MB)

    ekev_kernel<<<128, 256, 0, stream>>>(relE, Wr, Wvv, Ek, Ev);
    mcat_kernel<<<256, 256, 0, stream>>>(Wq, Ek, Mcat);
    projT_kernel<<<320, 256, 0, stream>>>(q, Wq, Wk, Wv, Mcat, Xq, Xk, Xv, T);
    biassmqk_kernel<<<1024, 256, 0, stream>>>(link, T, Xq, Xk, mask, alpha, S);
    zout_kernel<<<512, 256, 0, stream>>>(alpha, Xv, S, Ev, Wo, q, gamma, beta, out);
}

// Round 2
// 216.570 us; speedup vs baseline: 2.0829x; 2.0829x over previous
//
#include <hip/hip_runtime.h>
#include <math.h>

// B=4, N=256, D=256, H=8, DK=32, DV=32, R=64
constexpr int B_ = 4, N_ = 256, D_ = 256, H_ = 8, DK_ = 32, DV_ = 32, R_ = 64;
constexpr float SCALE_ = 0.17677669529663687f;  // 1/sqrt(32)
constexpr float EPS_ = 1e-6f;

// ---------------------------------------------------------------------------
// K1: Ek = relationE @ Wr, Ev = relationE @ Wvv   ([64,256] @ [256,256])
__global__ __launch_bounds__(256) void ekev_kernel(
        const float* __restrict__ relE, const float* __restrict__ Wr,
        const float* __restrict__ Wvv, float* __restrict__ Ek,
        float* __restrict__ Ev) {
    int r = blockIdx.x & 63;
    int which = blockIdx.x >> 6;
    const float* W = which ? Wvv : Wr;
    float* out = which ? Ev : Ek;
    __shared__ float row[256];
    int tid = threadIdx.x;
    row[tid] = relE[r * 256 + tid];
    __syncthreads();
    float acc = 0.f;
    for (int d = 0; d < 256; ++d) acc += row[d] * W[d * 256 + tid];
    out[r * 256 + tid] = acc;
}

// ---------------------------------------------------------------------------
// K2: Mcat[d, h*64+r] = sum_dk Wq[d, h*32+dk] * Ek[r, h*32+dk]
__global__ __launch_bounds__(256) void mcat_kernel(
        const float* __restrict__ Wq, const float* __restrict__ Ek,
        float* __restrict__ M) {
    int d = blockIdx.x;
    int t = threadIdx.x;
    __shared__ float wrow[256];
    wrow[t] = Wq[d * 256 + t];
    __syncthreads();
    for (int hr = t; hr < 512; hr += 256) {
        int h = hr >> 6, r = hr & 63;
        const float4* ek4 = (const float4*)(Ek + r * 256 + h * 32);
        const float4* w4 = (const float4*)(wrow + h * 32);
        float acc = 0.f;
#pragma unroll
        for (int k = 0; k < 8; ++k) {
            float4 e = ek4[k], w = w4[k];
            acc += e.x * w.x + e.y * w.y + e.z * w.z + e.w * w.w;
        }
        M[d * 512 + hr] = acc;
    }
}

// ---------------------------------------------------------------------------
// K3: fused projection GEMM: [1024 x 1280] = q[1024,256] @ cat(Wq,Wk,Wv,Mcat)
// 64x64 tile, 16x16 threads, 4x4 acc. grid = 20*16 = 320.
__global__ __launch_bounds__(256) void projT_kernel(
        const float* __restrict__ q, const float* __restrict__ Wq,
        const float* __restrict__ Wk, const float* __restrict__ Wv,
        const float* __restrict__ M, float* __restrict__ Xq,
        float* __restrict__ Xk, float* __restrict__ Xv,
        float* __restrict__ T) {
    int ct = blockIdx.x >> 4, rt = blockIdx.x & 15;
    int t = threadIdx.x;
    __shared__ float ash[32 * 65];
    __shared__ float bsh[32 * 64];
    const float* W;
    int ncols, cbase;
    if (ct < 4)       { W = Wq; cbase = ct * 64;        ncols = 256; }
    else if (ct < 8)  { W = Wk; cbase = (ct - 4) * 64;  ncols = 256; }
    else if (ct < 12) { W = Wv; cbase = (ct - 8) * 64;  ncols = 256; }
    else              { W = M;  cbase = (ct - 12) * 64; ncols = 512; }
    int ti = t >> 4, tj = t & 15;
    float acc[4][4] = {{0.f}};
    for (int kc = 0; kc < 8; ++kc) {
        __syncthreads();
#pragma unroll
        for (int kk = 0; kk < 2; ++kk) {
            int m = t + kk * 256;
            int i = m >> 3, kq = m & 7;
            float4 v = *(const float4*)(q + (size_t)(rt * 64 + i) * 256 + kc * 32 + kq * 4);
            ash[(kq * 4 + 0) * 65 + i] = v.x;
            ash[(kq * 4 + 1) * 65 + i] = v.y;
            ash[(kq * 4 + 2) * 65 + i] = v.z;
            ash[(kq * 4 + 3) * 65 + i] = v.w;
        }
#pragma unroll
        for (int kk = 0; kk < 2; ++kk) {
            int m = t + kk * 256;
            int k = m >> 4, j4 = m & 15;
            float4 v = *(const float4*)(W + (size_t)(kc * 32 + k) * ncols + cbase + j4 * 4);
            *(float4*)(bsh + k * 64 + j4 * 4) = v;
        }
        __syncthreads();
#pragma unroll 8
        for (int k = 0; k < 32; ++k) {
            float4 av = *(const float4*)(ash + k * 65 + ti * 4);
            float4 bv = *(const float4*)(bsh + k * 64 + tj * 4);
            acc[0][0] += av.x * bv.x; acc[0][1] += av.x * bv.y;
            acc[0][2] += av.x * bv.z; acc[0][3] += av.x * bv.w;
            acc[1][0] += av.y * bv.x; acc[1][1] += av.y * bv.y;
            acc[1][2] += av.y * bv.z; acc[1][3] += av.y * bv.w;
            acc[2][0] += av.z * bv.x; acc[2][1] += av.z * bv.y;
            acc[2][2] += av.z * bv.z; acc[2][3] += av.z * bv.w;
            acc[3][0] += av.w * bv.x; acc[3][1] += av.w * bv.y;
            acc[3][2] += av.w * bv.z; acc[3][3] += av.w * bv.w;
        }
    }
    if (ct < 12) {
        float* dst = (ct < 4) ? Xq : (ct < 8) ? Xk : Xv;
        int gcol = (ct & 3) * 64 + tj * 4;
        int h = gcol >> 5, dk = gcol & 31;
#pragma unroll
        for (int a = 0; a < 4; ++a) {
            int row = rt * 64 + ti * 4 + a;
            int bb = row >> 8, n = row & 255;
            *(float4*)(dst + ((size_t)(bb * 8 + h) * 256 + n) * 32 + dk) =
                make_float4(acc[a][0], acc[a][1], acc[a][2], acc[a][3]);
        }
    } else {
        int gcol = (ct - 12) * 64 + tj * 4;
#pragma unroll
        for (int a = 0; a < 4; ++a) {
            int row = rt * 64 + ti * 4 + a;
            *(float4*)(T + (size_t)row * 512 + gcol) =
                make_float4(acc[a][0], acc[a][1], acc[a][2], acc[a][3]);
        }
    }
}

// ---------------------------------------------------------------------------
// K4: qk[b,h,i,j] = Xq[b,h,i,:].Xk[b,h,j,:]  — batched tiled GEMM, K=32
// grid = 512, block = 256 (16x16), 4x4 outs
__global__ __launch_bounds__(256) void qk_kernel(
        const float* __restrict__ Xq, const float* __restrict__ Xk,
        float* __restrict__ qk) {
    int x = blockIdx.x;
    int jt = x & 3, it = (x >> 2) & 3, bh = x >> 4;
    int t = threadIdx.x;
    __shared__ float xqsh[32 * 64];
    __shared__ float xksh[32 * 64];
#pragma unroll
    for (int k = 0; k < 2; ++k) {
        int m = t + k * 256;
        int i = m >> 3, dq4 = m & 7;
        float4 v = *(const float4*)(Xq + ((size_t)(bh * 256 + it * 64 + i)) * 32 + dq4 * 4);
        xqsh[(dq4 * 4 + 0) * 64 + i] = v.x;
        xqsh[(dq4 * 4 + 1) * 64 + i] = v.y;
        xqsh[(dq4 * 4 + 2) * 64 + i] = v.z;
        xqsh[(dq4 * 4 + 3) * 64 + i] = v.w;
        float4 u = *(const float4*)(Xk + ((size_t)(bh * 256 + jt * 64 + i)) * 32 + dq4 * 4);
        xksh[(dq4 * 4 + 0) * 64 + i] = u.x;
        xksh[(dq4 * 4 + 1) * 64 + i] = u.y;
        xksh[(dq4 * 4 + 2) * 64 + i] = u.z;
        xksh[(dq4 * 4 + 3) * 64 + i] = u.w;
    }
    __syncthreads();
    int ti = t >> 4, tj = t & 15;
    float acc[4][4] = {{0.f}};
#pragma unroll 8
    for (int dk = 0; dk < 32; ++dk) {
        float4 av = *(const float4*)(xqsh + dk * 64 + ti * 4);
        float4 bv = *(const float4*)(xksh + dk * 64 + tj * 4);
        acc[0][0] += av.x * bv.x; acc[0][1] += av.x * bv.y;
        acc[0][2] += av.x * bv.z; acc[0][3] += av.x * bv.w;
        acc[1][0] += av.y * bv.x; acc[1][1] += av.y * bv.y;
        acc[1][2] += av.y * bv.z; acc[1][3] += av.y * bv.w;
        acc[2][0] += av.z * bv.x; acc[2][1] += av.z * bv.y;
        acc[2][2] += av.z * bv.z; acc[2][3] += av.z * bv.w;
        acc[3][0] += av.w * bv.x; acc[3][1] += av.w * bv.y;
        acc[3][2] += av.w * bv.z; acc[3][3] += av.w * bv.w;
    }
#pragma unroll
    for (int a = 0; a < 4; ++a) {
        int i = it * 64 + ti * 4 + a;
        *(float4*)(qk + ((size_t)(bh * 256 + i)) * 256 + jt * 64 + tj * 4) =
            make_float4(acc[a][0], acc[a][1], acc[a][2], acc[a][3]);
    }
}

// ---------------------------------------------------------------------------
// K5: fused bias + softmax + S per (b,i). grid = 1024, block = 256 (4 waves).
// Bias phase: thread t owns column j = t and reads its OWN 64 link floats
// directly from global (L3/L2-resident, streamed once) — no LDS staging, no
// chunk barriers, no cross-wave partial reduction. T row is LDS-broadcast
// (same-address across lanes = free). LDS ~19 KB -> 8 blk/CU.
__global__ __launch_bounds__(256) void biassm_kernel(
        const float* __restrict__ link, const float* __restrict__ Tg,
        const float* __restrict__ qk, const int* __restrict__ mask,
        float* __restrict__ alpha, float* __restrict__ S) {
    int bi = blockIdx.x;
    int b = bi >> 8, i = bi & 255;
    int t = threadIdx.x;
    __shared__ float Tsh[512];           // 2 KB
    __shared__ float ashm[2048];         // alpha [h][j] 8 KB
    __shared__ float part[2048];         // S partials 8 KB
    __shared__ float redsh[64];
    Tsh[t] = Tg[(size_t)bi * 512 + t];
    Tsh[256 + t] = Tg[(size_t)bi * 512 + 256 + t];

    // issue qk + mask loads early (8+1 scalars, coalesced across t)
    float qv[8];
#pragma unroll
    for (int h = 0; h < 8; ++h)
        qv[h] = qk[((size_t)(b * 8 + h) * 256 + i) * 256 + t];
    int mv = mask[((size_t)(b * 256 + i)) * 256 + t];
    __syncthreads();                                            // B1 (Tsh)

    // ---- bias: s[h] = sum_r link[bi, j=t, r] * T[h*64+r], zero barriers ----
    float s[8] = {0.f, 0.f, 0.f, 0.f, 0.f, 0.f, 0.f, 0.f};
    {
        const float4* l4 = (const float4*)(link + ((size_t)(bi * 256 + t)) * 64);
        const float4* T4 = (const float4*)Tsh;
#pragma unroll 4
        for (int k = 0; k < 16; ++k) {
            float4 lv = l4[k];
#pragma unroll
            for (int h = 0; h < 8; ++h) {
                float4 tv = T4[h * 16 + k];
                s[h] += lv.x * tv.x + lv.y * tv.y + lv.z * tv.z + lv.w * tv.w;
            }
        }
    }
#pragma unroll
    for (int h = 0; h < 8; ++h) {
        s[h] = (qv[h] + s[h]) * SCALE_;
        if (mv == 0) s[h] = -1e9f;
    }

    // ---- softmax (thread = j) ----
    int lane = t & 63, wv = t >> 6;
#pragma unroll
    for (int h = 0; h < 8; ++h) {
        float v = s[h];
        for (int off = 32; off > 0; off >>= 1) v = fmaxf(v, __shfl_xor(v, off));
        if (lane == 0) redsh[h * 4 + wv] = v;
    }
    __syncthreads();                                            // B2
    float mx[8];
#pragma unroll
    for (int h = 0; h < 8; ++h)
        mx[h] = fmaxf(fmaxf(redsh[h * 4 + 0], redsh[h * 4 + 1]),
                      fmaxf(redsh[h * 4 + 2], redsh[h * 4 + 3]));
#pragma unroll
    for (int h = 0; h < 8; ++h) {
        float e = __expf(s[h] - mx[h]);
        s[h] = e;
        float v = e;
        for (int off = 32; off > 0; off >>= 1) v += __shfl_xor(v, off);
        if (lane == 0) redsh[32 + h * 4 + wv] = v;
    }
    __syncthreads();                                            // B3
#pragma unroll
    for (int h = 0; h < 8; ++h) {
        float esum = redsh[32 + h * 4 + 0] + redsh[32 + h * 4 + 1] +
                     redsh[32 + h * 4 + 2] + redsh[32 + h * 4 + 3];
        float a = s[h] * (1.f / esum);
        ashm[h * 256 + t] = a;
        alpha[((size_t)(b * 8 + h) * 256 + i) * 256 + t] = a;
    }
    __syncthreads();                                            // B4

    // ---- S (wave g owns j in [64g, 64g+64), lane = r; coalesced, L3-hot) ----
    int r = t & 63, g = t >> 6;
    float pacc2[8] = {0.f, 0.f, 0.f, 0.f, 0.f, 0.f, 0.f, 0.f};
    const float* lp2 = link + ((size_t)(bi * 256 + g * 64)) * 64 + r;
#pragma unroll 4
    for (int j4 = 0; j4 < 16; ++j4) {
        float l0 = lp2[(j4 * 4 + 0) * 64];
        float l1 = lp2[(j4 * 4 + 1) * 64];
        float l2 = lp2[(j4 * 4 + 2) * 64];
        float l3 = lp2[(j4 * 4 + 3) * 64];
#pragma unroll
        for (int h = 0; h < 8; ++h) {
            float4 a = *(const float4*)(ashm + h * 256 + g * 64 + j4 * 4);
            pacc2[h] += a.x * l0 + a.y * l1 + a.z * l2 + a.w * l3;
        }
    }
#pragma unroll
    for (int h = 0; h < 8; ++h) part[g * 512 + h * 64 + r] = pacc2[h];
    __syncthreads();                                            // B5
    for (int hr = t; hr < 512; hr += 256) {
        S[(size_t)bi * 512 + hr] =
            part[hr] + part[512 + hr] + part[1024 + hr] + part[1536 + hr];
    }
}

// ---------------------------------------------------------------------------
// K6: fused Z + output: Z[h][dv] = alpha.Xv + S.Ev, then @Wo + residual -> LN.
// grid = 512 (2 rows each), block = 256.
__global__ __launch_bounds__(256) void zout_kernel(
        const float* __restrict__ alpha, const float* __restrict__ Xv,
        const float* __restrict__ S, const float* __restrict__ Ev,
        const float* __restrict__ Wo, const float* __restrict__ q,
        const float* __restrict__ gamma, const float* __restrict__ beta,
        float* __restrict__ out) {
    int blk = blockIdx.x;
    int row0 = blk * 2;                 // rows row0, row0+1 (same b)
    int b = row0 >> 8;
    int t = threadIdx.x;
    __shared__ float Ssh[2 * 512];      // 4 KB
    __shared__ float ashm[2 * 2048];    // alpha [rr][h][j] 16 KB
    __shared__ float zsh[2 * 256];      // 2 KB
    __shared__ float redsh[16];
    for (int m = t; m < 1024; m += 256)
        Ssh[m] = S[(size_t)(row0 + (m >> 9)) * 512 + (m & 511)];
    for (int m = t; m < 4096; m += 256) {
        int rr = m >> 11, h = (m >> 8) & 7, j = m & 255;
        ashm[m] = alpha[((size_t)(b * 8 + h) * 256 + ((row0 + rr) & 255)) * 256 + j];
    }
    __syncthreads();
    // phase 1: Z for both rows
    {
        int h = t >> 5, dv = t & 31;
        float z0 = 0.f, z1 = 0.f;
        const float* xv = Xv + ((size_t)(b * 8 + h) * 256) * 32 + dv;
#pragma unroll 4
        for (int j = 0; j < 256; ++j) {
            float x = xv[j * 32];
            z0 += ashm[h * 256 + j] * x;
            z1 += ashm[2048 + h * 256 + j] * x;
        }
#pragma unroll 4
        for (int r = 0; r < 64; ++r) {
            float ev = Ev[r * 256 + h * 32 + dv];
            z0 += Ssh[h * 64 + r] * ev;
            z1 += Ssh[512 + h * 64 + r] * ev;
        }
        zsh[t] = z0;
        zsh[256 + t] = z1;
    }
    __syncthreads();
    // phase 2: @Wo + residual + LayerNorm (col = t)
    float a0 = q[(size_t)row0 * 256 + t];
    float a1 = q[(size_t)(row0 + 1) * 256 + t];
    for (int d4 = 0; d4 < 64; ++d4) {
        float w0 = Wo[(d4 * 4 + 0) * 256 + t];
        float w1 = Wo[(d4 * 4 + 1) * 256 + t];
        float w2 = Wo[(d4 * 4 + 2) * 256 + t];
        float w3 = Wo[(d4 * 4 + 3) * 256 + t];
        float4 z0v = *(const float4*)(zsh + d4 * 4);
        float4 z1v = *(const float4*)(zsh + 256 + d4 * 4);
        a0 += z0v.x * w0 + z0v.y * w1 + z0v.z * w2 + z0v.w * w3;
        a1 += z1v.x * w0 + z1v.y * w1 + z1v.z * w2 + z1v.w * w3;
    }
    int lane = t & 63, wv = t >> 6;
    float acc2[2] = {a0, a1};
#pragma unroll
    for (int rr = 0; rr < 2; ++rr) {
        float v = acc2[rr], v2 = acc2[rr] * acc2[rr];
        for (int off = 32; off > 0; off >>= 1) {
            v += __shfl_xor(v, off);
            v2 += __shfl_xor(v2, off);
        }
        if (lane == 0) {
            redsh[rr * 8 + wv] = v;
            redsh[rr * 8 + 4 + wv] = v2;
        }
    }
    __syncthreads();
#pragma unroll
    for (int rr = 0; rr < 2; ++rr) {
        float sum = redsh[rr * 8 + 0] + redsh[rr * 8 + 1] + redsh[rr * 8 + 2] + redsh[rr * 8 + 3];
        float sum2 = redsh[rr * 8 + 4] + redsh[rr * 8 + 5] + redsh[rr * 8 + 6] + redsh[rr * 8 + 7];
        float mu = sum * (1.f / 256.f);
        float var = sum2 * (1.f / 256.f) - mu * mu;
        float dev = acc2[rr] - mu;
        out[(size_t)(row0 + rr) * 256 + t] = dev * rsqrtf(var + EPS_) * gamma[t] + beta[t];
    }
}

// ---------------------------------------------------------------------------
extern "C" void kernel_launch(void* const* d_in, const int* in_sizes, int n_in,
                              void* d_out, int out_size, void* d_ws, size_t ws_size,
                              hipStream_t stream) {
    const float* q     = (const float*)d_in[0];
    const int*   mask  = (const int*)d_in[3];
    const float* link  = (const float*)d_in[4];
    const float* Wq    = (const float*)d_in[5];
    const float* Wk    = (const float*)d_in[6];
    const float* Wr    = (const float*)d_in[7];
    const float* Wv    = (const float*)d_in[8];
    const float* Wvv   = (const float*)d_in[9];
    const float* relE  = (const float*)d_in[10];
    const float* Wo    = (const float*)d_in[11];
    const float* gamma = (const float*)d_in[12];
    const float* beta  = (const float*)d_in[13];

    float* out   = (float*)d_out;
    float* alpha = out + B_ * N_ * D_;      // second output [B,H,N,N]

    float* ws    = (float*)d_ws;
    float* Ek    = ws;                         // 16384
    float* Ev    = Ek + 16384;                 // 16384
    float* Mcat  = Ev + 16384;                 // 131072
    float* Xq    = Mcat + 131072;              // 262144
    float* Xk    = Xq + 262144;                // 262144
    float* Xv    = Xk + 262144;                // 262144
    float* T     = Xv + 262144;                // 524288
    float* qkbuf = T + 524288;                 // 2097152
    float* S     = qkbuf + 2097152;            // 524288  (total ~15.5 MB)

    ekev_kernel<<<128, 256, 0, stream>>>(relE, Wr, Wvv, Ek, Ev);
    mcat_kernel<<<256, 256, 0, stream>>>(Wq, Ek, Mcat);
    projT_kernel<<<320, 256, 0, stream>>>(q, Wq, Wk, Wv, Mcat, Xq, Xk, Xv, T);
    qk_kernel<<<512, 256, 0, stream>>>(Xq, Xk, qkbuf);
    biassm_kernel<<<1024, 256, 0, stream>>>(link, T, qkbuf, mask, alpha, S);
    zout_kernel<<<512, 256, 0, stream>>>(alpha, Xv, S, Ev, Wo, q, gamma, beta, out);
}

// Round 3
// 208.223 us; speedup vs baseline: 2.1664x; 1.0401x over previous
//
#include <hip/hip_runtime.h>
#include <math.h>

// B=4, N=256, D=256, H=8, DK=32, DV=32, R=64
constexpr int B_ = 4, N_ = 256, D_ = 256, H_ = 8, DK_ = 32, DV_ = 32, R_ = 64;
constexpr float SCALE_ = 0.17677669529663687f;  // 1/sqrt(32)
constexpr float EPS_ = 1e-6f;

// ---------------------------------------------------------------------------
// K1: Ek = relationE @ Wr, Ev = relationE @ Wvv   ([64,256] @ [256,256])
__global__ __launch_bounds__(256) void ekev_kernel(
        const float* __restrict__ relE, const float* __restrict__ Wr,
        const float* __restrict__ Wvv, float* __restrict__ Ek,
        float* __restrict__ Ev) {
    int r = blockIdx.x & 63;
    int which = blockIdx.x >> 6;
    const float* W = which ? Wvv : Wr;
    float* out = which ? Ev : Ek;
    __shared__ float row[256];
    int tid = threadIdx.x;
    row[tid] = relE[r * 256 + tid];
    __syncthreads();
    float acc = 0.f;
#pragma unroll 4
    for (int d = 0; d < 256; ++d) acc += row[d] * W[d * 256 + tid];
    out[r * 256 + tid] = acc;
}

// ---------------------------------------------------------------------------
// K2: projection GEMM: [1024 x 768] = q[1024,256] @ cat(Wq,Wk,Wv)
// 64x64 tile, 16x16 threads, 4x4 acc. grid = 12*16 = 192. (Mcat/T removed:
// T is now computed in qkT_kernel directly from Xq and Ek.)
__global__ __launch_bounds__(256) void projT_kernel(
        const float* __restrict__ q, const float* __restrict__ Wq,
        const float* __restrict__ Wk, const float* __restrict__ Wv,
        float* __restrict__ Xq, float* __restrict__ Xk,
        float* __restrict__ Xv) {
    int ct = blockIdx.x >> 4, rt = blockIdx.x & 15;
    int t = threadIdx.x;
    __shared__ float ash[32 * 65];
    __shared__ float bsh[32 * 64];
    const float* W;
    int cbase;
    if (ct < 4)       { W = Wq; cbase = ct * 64; }
    else if (ct < 8)  { W = Wk; cbase = (ct - 4) * 64; }
    else              { W = Wv; cbase = (ct - 8) * 64; }
    int ti = t >> 4, tj = t & 15;
    float acc[4][4] = {{0.f}};
    for (int kc = 0; kc < 8; ++kc) {
        __syncthreads();
#pragma unroll
        for (int kk = 0; kk < 2; ++kk) {
            int m = t + kk * 256;
            int i = m >> 3, kq = m & 7;
            float4 v = *(const float4*)(q + (size_t)(rt * 64 + i) * 256 + kc * 32 + kq * 4);
            ash[(kq * 4 + 0) * 65 + i] = v.x;
            ash[(kq * 4 + 1) * 65 + i] = v.y;
            ash[(kq * 4 + 2) * 65 + i] = v.z;
            ash[(kq * 4 + 3) * 65 + i] = v.w;
        }
#pragma unroll
        for (int kk = 0; kk < 2; ++kk) {
            int m = t + kk * 256;
            int k = m >> 4, j4 = m & 15;
            float4 v = *(const float4*)(W + (size_t)(kc * 32 + k) * 256 + cbase + j4 * 4);
            *(float4*)(bsh + k * 64 + j4 * 4) = v;
        }
        __syncthreads();
#pragma unroll 8
        for (int k = 0; k < 32; ++k) {
            float4 av = *(const float4*)(ash + k * 65 + ti * 4);
            float4 bv = *(const float4*)(bsh + k * 64 + tj * 4);
            acc[0][0] += av.x * bv.x; acc[0][1] += av.x * bv.y;
            acc[0][2] += av.x * bv.z; acc[0][3] += av.x * bv.w;
            acc[1][0] += av.y * bv.x; acc[1][1] += av.y * bv.y;
            acc[1][2] += av.y * bv.z; acc[1][3] += av.y * bv.w;
            acc[2][0] += av.z * bv.x; acc[2][1] += av.z * bv.y;
            acc[2][2] += av.z * bv.z; acc[2][3] += av.z * bv.w;
            acc[3][0] += av.w * bv.x; acc[3][1] += av.w * bv.y;
            acc[3][2] += av.w * bv.z; acc[3][3] += av.w * bv.w;
        }
    }
    float* dst = (ct < 4) ? Xq : (ct < 8) ? Xk : Xv;
    int gcol = (ct & 3) * 64 + tj * 4;
    int h = gcol >> 5, dk = gcol & 31;
#pragma unroll
    for (int a = 0; a < 4; ++a) {
        int row = rt * 64 + ti * 4 + a;
        int bb = row >> 8, n = row & 255;
        *(float4*)(dst + ((size_t)(bb * 8 + h) * 256 + n) * 32 + dk) =
            make_float4(acc[a][0], acc[a][1], acc[a][2], acc[a][3]);
    }
}

// ---------------------------------------------------------------------------
// K3: qk[b,h,i,j] = Xq[b,h,i,:].Xk[b,h,j,:]  — batched tiled GEMM, K=32.
// jt==0 blocks additionally compute T[bi, h*64+r] = sum_dk Xq[b,h,i,dk]*
// Ek[r, h*32+dk] (reuses the staged Xq^T tile; Ek_h tile = 8 KB LDS).
// grid = 512, block = 256 (16x16), 4x4 outs.
__global__ __launch_bounds__(256) void qkT_kernel(
        const float* __restrict__ Xq, const float* __restrict__ Xk,
        const float* __restrict__ Ek, float* __restrict__ qk,
        float* __restrict__ T) {
    int x = blockIdx.x;
    int jt = x & 3, it = (x >> 2) & 3, bh = x >> 4;
    int b = bh >> 3, h = bh & 7;
    int t = threadIdx.x;
    __shared__ float xqsh[32 * 64];
    __shared__ float xksh[32 * 64];
    __shared__ float eksh[32 * 64];
#pragma unroll
    for (int k = 0; k < 2; ++k) {
        int m = t + k * 256;
        int i = m >> 3, dq4 = m & 7;
        float4 v = *(const float4*)(Xq + ((size_t)(bh * 256 + it * 64 + i)) * 32 + dq4 * 4);
        xqsh[(dq4 * 4 + 0) * 64 + i] = v.x;
        xqsh[(dq4 * 4 + 1) * 64 + i] = v.y;
        xqsh[(dq4 * 4 + 2) * 64 + i] = v.z;
        xqsh[(dq4 * 4 + 3) * 64 + i] = v.w;
        float4 u = *(const float4*)(Xk + ((size_t)(bh * 256 + jt * 64 + i)) * 32 + dq4 * 4);
        xksh[(dq4 * 4 + 0) * 64 + i] = u.x;
        xksh[(dq4 * 4 + 1) * 64 + i] = u.y;
        xksh[(dq4 * 4 + 2) * 64 + i] = u.z;
        xksh[(dq4 * 4 + 3) * 64 + i] = u.w;
    }
    if (jt == 0) {
        // stage Ek_h transposed: eksh[dk*64 + r] = Ek[r*256 + h*32 + dk]
        int r = t >> 2, dq = t & 3;
#pragma unroll
        for (int kk = 0; kk < 2; ++kk) {
            int dq4 = dq + kk * 4;  // 0..7
            float4 v = *(const float4*)(Ek + r * 256 + h * 32 + dq4 * 4);
            eksh[(dq4 * 4 + 0) * 64 + r] = v.x;
            eksh[(dq4 * 4 + 1) * 64 + r] = v.y;
            eksh[(dq4 * 4 + 2) * 64 + r] = v.z;
            eksh[(dq4 * 4 + 3) * 64 + r] = v.w;
        }
    }
    __syncthreads();
    int ti = t >> 4, tj = t & 15;
    float acc[4][4] = {{0.f}};
#pragma unroll 8
    for (int dk = 0; dk < 32; ++dk) {
        float4 av = *(const float4*)(xqsh + dk * 64 + ti * 4);
        float4 bv = *(const float4*)(xksh + dk * 64 + tj * 4);
        acc[0][0] += av.x * bv.x; acc[0][1] += av.x * bv.y;
        acc[0][2] += av.x * bv.z; acc[0][3] += av.x * bv.w;
        acc[1][0] += av.y * bv.x; acc[1][1] += av.y * bv.y;
        acc[1][2] += av.y * bv.z; acc[1][3] += av.y * bv.w;
        acc[2][0] += av.z * bv.x; acc[2][1] += av.z * bv.y;
        acc[2][2] += av.z * bv.z; acc[2][3] += av.z * bv.w;
        acc[3][0] += av.w * bv.x; acc[3][1] += av.w * bv.y;
        acc[3][2] += av.w * bv.z; acc[3][3] += av.w * bv.w;
    }
#pragma unroll
    for (int a = 0; a < 4; ++a) {
        int i = it * 64 + ti * 4 + a;
        *(float4*)(qk + ((size_t)(bh * 256 + i)) * 256 + jt * 64 + tj * 4) =
            make_float4(acc[a][0], acc[a][1], acc[a][2], acc[a][3]);
    }
    if (jt == 0) {
        float tacc[4][4] = {{0.f}};
#pragma unroll 8
        for (int dk = 0; dk < 32; ++dk) {
            float4 av = *(const float4*)(xqsh + dk * 64 + ti * 4);
            float4 ev = *(const float4*)(eksh + dk * 64 + tj * 4);
            tacc[0][0] += av.x * ev.x; tacc[0][1] += av.x * ev.y;
            tacc[0][2] += av.x * ev.z; tacc[0][3] += av.x * ev.w;
            tacc[1][0] += av.y * ev.x; tacc[1][1] += av.y * ev.y;
            tacc[1][2] += av.y * ev.z; tacc[1][3] += av.y * ev.w;
            tacc[2][0] += av.z * ev.x; tacc[2][1] += av.z * ev.y;
            tacc[2][2] += av.z * ev.z; tacc[2][3] += av.z * ev.w;
            tacc[3][0] += av.w * ev.x; tacc[3][1] += av.w * ev.y;
            tacc[3][2] += av.w * ev.z; tacc[3][3] += av.w * ev.w;
        }
#pragma unroll
        for (int a = 0; a < 4; ++a) {
            int i = it * 64 + ti * 4 + a;
            *(float4*)(T + ((size_t)(b * 256 + i)) * 512 + h * 64 + tj * 4) =
                make_float4(tacc[a][0], tacc[a][1], tacc[a][2], tacc[a][3]);
        }
    }
}

// ---------------------------------------------------------------------------
// K4: fused bias + softmax + S + Z per (b,i). grid = 1024, block = 256.
// Bias: thread t owns j=t, reads its own 64 link floats direct from global.
// After softmax (alpha in LDS), S = alpha^T.link partials per wave, reduced
// into Tsh (T is dead), then Z[h][dv] = alpha.Xv + S.Ev computed in-block —
// this kills zout's 33 MB alpha re-read and the S global buffer entirely.
__global__ __launch_bounds__(256) void biassmz_kernel(
        const float* __restrict__ link, const float* __restrict__ Tg,
        const float* __restrict__ qk, const int* __restrict__ mask,
        const float* __restrict__ Xv, const float* __restrict__ Ev,
        float* __restrict__ alpha, float* __restrict__ Z) {
    int bi = blockIdx.x;
    int b = bi >> 8, i = bi & 255;
    int t = threadIdx.x;
    __shared__ float Tsh[512];           // 2 KB; reused for S after B5
    __shared__ float ashm[2048];         // alpha [h][j] 8 KB
    __shared__ float part[2048];         // S partials 8 KB
    __shared__ float redsh[64];
    Tsh[t] = Tg[(size_t)bi * 512 + t];
    Tsh[256 + t] = Tg[(size_t)bi * 512 + 256 + t];

    // issue qk + mask loads early (coalesced across t)
    float qv[8];
#pragma unroll
    for (int h = 0; h < 8; ++h)
        qv[h] = qk[((size_t)(b * 8 + h) * 256 + i) * 256 + t];
    int mv = mask[((size_t)(b * 256 + i)) * 256 + t];
    __syncthreads();                                            // B1 (Tsh)

    // ---- bias: s[h] = sum_r link[bi, j=t, r] * T[h*64+r] ----
    float s[8] = {0.f, 0.f, 0.f, 0.f, 0.f, 0.f, 0.f, 0.f};
    {
        const float4* l4 = (const float4*)(link + ((size_t)(bi * 256 + t)) * 64);
        const float4* T4 = (const float4*)Tsh;
#pragma unroll 8
        for (int k = 0; k < 16; ++k) {
            float4 lv = l4[k];
#pragma unroll
            for (int h = 0; h < 8; ++h) {
                float4 tv = T4[h * 16 + k];
                s[h] += lv.x * tv.x + lv.y * tv.y + lv.z * tv.z + lv.w * tv.w;
            }
        }
    }
#pragma unroll
    for (int h = 0; h < 8; ++h) {
        s[h] = (qv[h] + s[h]) * SCALE_;
        if (mv == 0) s[h] = -1e9f;
    }

    // ---- softmax (thread = j) ----
    int lane = t & 63, wv = t >> 6;
#pragma unroll
    for (int h = 0; h < 8; ++h) {
        float v = s[h];
        for (int off = 32; off > 0; off >>= 1) v = fmaxf(v, __shfl_xor(v, off));
        if (lane == 0) redsh[h * 4 + wv] = v;
    }
    __syncthreads();                                            // B2
    float mx[8];
#pragma unroll
    for (int h = 0; h < 8; ++h)
        mx[h] = fmaxf(fmaxf(redsh[h * 4 + 0], redsh[h * 4 + 1]),
                      fmaxf(redsh[h * 4 + 2], redsh[h * 4 + 3]));
#pragma unroll
    for (int h = 0; h < 8; ++h) {
        float e = __expf(s[h] - mx[h]);
        s[h] = e;
        float v = e;
        for (int off = 32; off > 0; off >>= 1) v += __shfl_xor(v, off);
        if (lane == 0) redsh[32 + h * 4 + wv] = v;
    }
    __syncthreads();                                            // B3
#pragma unroll
    for (int h = 0; h < 8; ++h) {
        float esum = redsh[32 + h * 4 + 0] + redsh[32 + h * 4 + 1] +
                     redsh[32 + h * 4 + 2] + redsh[32 + h * 4 + 3];
        float a = s[h] * (1.f / esum);
        ashm[h * 256 + t] = a;
        alpha[((size_t)(b * 8 + h) * 256 + i) * 256 + t] = a;
    }
    __syncthreads();                                            // B4

    // ---- S partials (wave g owns j in [64g, 64g+64), lane = r) ----
    int r = t & 63, g = t >> 6;
    {
        float pacc2[8] = {0.f, 0.f, 0.f, 0.f, 0.f, 0.f, 0.f, 0.f};
        const float* lp2 = link + ((size_t)(bi * 256 + g * 64)) * 64 + r;
#pragma unroll 4
        for (int j4 = 0; j4 < 16; ++j4) {
            float l0 = lp2[(j4 * 4 + 0) * 64];
            float l1 = lp2[(j4 * 4 + 1) * 64];
            float l2 = lp2[(j4 * 4 + 2) * 64];
            float l3 = lp2[(j4 * 4 + 3) * 64];
#pragma unroll
            for (int h = 0; h < 8; ++h) {
                float4 a = *(const float4*)(ashm + h * 256 + g * 64 + j4 * 4);
                pacc2[h] += a.x * l0 + a.y * l1 + a.z * l2 + a.w * l3;
            }
        }
#pragma unroll
        for (int h = 0; h < 8; ++h) part[g * 512 + h * 64 + r] = pacc2[h];
    }
    __syncthreads();                                            // B5
    // reduce S into Tsh (T values dead since the bias phase)
    for (int hr = t; hr < 512; hr += 256)
        Tsh[hr] = part[hr] + part[512 + hr] + part[1024 + hr] + part[1536 + hr];
    __syncthreads();                                            // B6

    // ---- Z[h][dv] = sum_j alpha[h,j]*Xv[b,h,j,dv] + sum_r S[h,r]*Ev[r,h*32+dv]
    {
        int h = t >> 5, dv = t & 31;
        float z = 0.f;
        const float* ap = ashm + h * 256;
        const float* xvp = Xv + ((size_t)(b * 8 + h) * 256) * 32 + dv;
#pragma unroll 4
        for (int j = 0; j < 256; ++j) z += ap[j] * xvp[j * 32];
        const float* sp = Tsh + h * 64;
        const float* evp = Ev + h * 32 + dv;
#pragma unroll 4
        for (int rr = 0; rr < 64; ++rr) z += sp[rr] * evp[rr * 256];
        Z[(size_t)bi * 256 + t] = z;
    }
}

// ---------------------------------------------------------------------------
// K5: out = LN(Z @ Wo + q). grid = 512 (2 rows each), block = 256.
__global__ __launch_bounds__(256) void out_kernel(
        const float* __restrict__ Z, const float* __restrict__ Wo,
        const float* __restrict__ q, const float* __restrict__ gamma,
        const float* __restrict__ beta, float* __restrict__ out) {
    int row0 = blockIdx.x * 2;
    int t = threadIdx.x;
    __shared__ float zsh[512];
    __shared__ float redsh[16];
    zsh[t] = Z[(size_t)row0 * 256 + t];
    zsh[256 + t] = Z[(size_t)row0 * 256 + 256 + t];
    __syncthreads();
    float a0 = q[(size_t)row0 * 256 + t];
    float a1 = q[(size_t)(row0 + 1) * 256 + t];
    for (int d4 = 0; d4 < 64; ++d4) {
        float w0 = Wo[(d4 * 4 + 0) * 256 + t];
        float w1 = Wo[(d4 * 4 + 1) * 256 + t];
        float w2 = Wo[(d4 * 4 + 2) * 256 + t];
        float w3 = Wo[(d4 * 4 + 3) * 256 + t];
        float4 z0v = *(const float4*)(zsh + d4 * 4);
        float4 z1v = *(const float4*)(zsh + 256 + d4 * 4);
        a0 += z0v.x * w0 + z0v.y * w1 + z0v.z * w2 + z0v.w * w3;
        a1 += z1v.x * w0 + z1v.y * w1 + z1v.z * w2 + z1v.w * w3;
    }
    int lane = t & 63, wv = t >> 6;
    float acc2[2] = {a0, a1};
#pragma unroll
    for (int rr = 0; rr < 2; ++rr) {
        float v = acc2[rr], v2 = acc2[rr] * acc2[rr];
        for (int off = 32; off > 0; off >>= 1) {
            v += __shfl_xor(v, off);
            v2 += __shfl_xor(v2, off);
        }
        if (lane == 0) {
            redsh[rr * 8 + wv] = v;
            redsh[rr * 8 + 4 + wv] = v2;
        }
    }
    __syncthreads();
#pragma unroll
    for (int rr = 0; rr < 2; ++rr) {
        float sum = redsh[rr * 8 + 0] + redsh[rr * 8 + 1] + redsh[rr * 8 + 2] + redsh[rr * 8 + 3];
        float sum2 = redsh[rr * 8 + 4] + redsh[rr * 8 + 5] + redsh[rr * 8 + 6] + redsh[rr * 8 + 7];
        float mu = sum * (1.f / 256.f);
        float var = sum2 * (1.f / 256.f) - mu * mu;
        float dev = acc2[rr] - mu;
        out[(size_t)(row0 + rr) * 256 + t] = dev * rsqrtf(var + EPS_) * gamma[t] + beta[t];
    }
}

// ---------------------------------------------------------------------------
extern "C" void kernel_launch(void* const* d_in, const int* in_sizes, int n_in,
                              void* d_out, int out_size, void* d_ws, size_t ws_size,
                              hipStream_t stream) {
    const float* q     = (const float*)d_in[0];
    const int*   mask  = (const int*)d_in[3];
    const float* link  = (const float*)d_in[4];
    const float* Wq    = (const float*)d_in[5];
    const float* Wk    = (const float*)d_in[6];
    const float* Wr    = (const float*)d_in[7];
    const float* Wv    = (const float*)d_in[8];
    const float* Wvv   = (const float*)d_in[9];
    const float* relE  = (const float*)d_in[10];
    const float* Wo    = (const float*)d_in[11];
    const float* gamma = (const float*)d_in[12];
    const float* beta  = (const float*)d_in[13];

    float* out   = (float*)d_out;
    float* alpha = out + B_ * N_ * D_;      // second output [B,H,N,N]

    float* ws    = (float*)d_ws;
    float* Ek    = ws;                         // 16384
    float* Ev    = Ek + 16384;                 // 16384
    float* Xq    = Ev + 16384;                 // 262144
    float* Xk    = Xq + 262144;                // 262144
    float* Xv    = Xk + 262144;                // 262144
    float* T     = Xv + 262144;                // 524288
    float* qkbuf = T + 524288;                 // 2097152
    float* Zbuf  = qkbuf + 2097152;            // 262144  (total ~14.1 MB)

    ekev_kernel<<<128, 256, 0, stream>>>(relE, Wr, Wvv, Ek, Ev);
    projT_kernel<<<192, 256, 0, stream>>>(q, Wq, Wk, Wv, Xq, Xk, Xv);
    qkT_kernel<<<512, 256, 0, stream>>>(Xq, Xk, Ek, qkbuf, T);
    biassmz_kernel<<<1024, 256, 0, stream>>>(link, T, qkbuf, mask, Xv, Ev, alpha, Zbuf);
    out_kernel<<<512, 256, 0, stream>>>(Zbuf, Wo, q, gamma, beta, out);
}